// Round 18
// baseline (16284.460 us; speedup 1.0000x reference)
//
#include <hip/hip_runtime.h>
#include <stdint.h>

typedef __attribute__((ext_vector_type(8))) short short8;
typedef __attribute__((ext_vector_type(4))) float f32x4;

#define NT 15

// packed bf16 weight fragments in d_ws (element offsets, shorts)
#define SET0 0          // L0: 32 (jt,g) pairs x 5 kt x 512
#define SET1 81920      // L1: 32 pairs x 8 kt x 512
#define SET2 212992     // dec: same shape as L1
#define SET3 344064
#define PK_TOTAL 346112
#define DD_OFF (PK_TOTAL*2)   // dbase[1280] | hw[768] | hb[6] | hc[6]  (floats)

__device__ __forceinline__ unsigned short f2bf(float f){
  unsigned int u = __builtin_bit_cast(unsigned int, f);
  u += 0x7fffu + ((u >> 16) & 1u);
  return (unsigned short)(u >> 16);
}
__device__ __forceinline__ float sigf(float x){
  return __builtin_amdgcn_rcpf(1.0f + __expf(-x));
}
__device__ __forceinline__ float tanhf_(float x){
  return 1.0f - 2.0f*__builtin_amdgcn_rcpf(1.0f + __expf(2.0f*x));
}
// XOR-swizzled LDS index (shorts) within a 16x128 wave-private tile.
__device__ __forceinline__ int sidx(int row, int col){
  return row*128 + (col ^ ((row & 7) << 3));
}

// ---------------- prep: pack weights to bf16 MFMA fragments ----------------
__global__ void pack_w(const float* __restrict__ Wih0, const float* __restrict__ Whh0,
                       const float* __restrict__ Wih1, const float* __restrict__ Whh1,
                       const float* __restrict__ Wihd, const float* __restrict__ Whhd,
                       const float* __restrict__ Wm,  const float* __restrict__ Ws,
                       unsigned short* __restrict__ pk)
{
  int idx = blockIdx.x*256 + threadIdx.x;
  if (idx >= PK_TOTAL) return;
  float v = 0.f;
  if (idx >= SET3){
    int e = idx - SET3;
    int j = e & 7, lane = (e >> 3) & 63, kt = e >> 9;
    int n = lane & 15;
    int k = kt*32 + (lane >> 4)*8 + j;
    if (n < 3) v = Wm[n*128 + k];
    else if (n < 6) v = Ws[(n-3)*128 + k];
  } else {
    int set, e;
    if (idx < SET1){ set = 0; e = idx; }
    else if (idx < SET2){ set = 1; e = idx - SET1; }
    else { set = 2; e = idx - SET2; }
    int j = e & 7, lane = (e >> 3) & 63, rest = e >> 9;
    int nf = (set == 0) ? 5 : 8;
    int kt = rest % nf, pair = rest / nf;
    int g = pair & 3, jt = pair >> 2;
    int n = g*128 + jt*16 + (lane & 15);
    int kk = (lane >> 4)*8 + j;
    if (set == 0){
      if (kt < 4) v = Whh0[n*128 + kt*32 + kk];
      else if (kk < 6) v = Wih0[n*6 + kk];
    } else {
      const float* Wi = (set == 1) ? Wih1 : Wihd;
      const float* Wh = (set == 1) ? Whh1 : Whhd;
      v = (kt < 4) ? Wi[n*128 + kt*32 + kk] : Wh[n*128 + (kt-4)*32 + kk];
    }
  }
  pk[idx] = f2bf(v);
}

// decoder constants (see r7)
__global__ void prep_dec(const float* __restrict__ emb, const float* __restrict__ Wp,
                         const float* __restrict__ bp,
                         const float* __restrict__ Wm, const float* __restrict__ Ws,
                         const float* __restrict__ bm, const float* __restrict__ bs,
                         const float* __restrict__ lng, const float* __restrict__ lnb,
                         float* __restrict__ dd)
{
  int idx = blockIdx.x*128 + threadIdx.x;
  if (idx < 1280){
    int s = idx >> 7, j = idx & 127;
    float acc = bp[j];
    for (int k = 0; k < 128; ++k) acc += emb[s*128 + k] * Wp[j*131 + 3 + k];
    dd[idx] = acc;
  } else if (idx < 2048){
    int e = idx - 1280; int o = e >> 7, j = e & 127;
    const float* W = (o < 3) ? (Wm + o*128) : (Ws + (o-3)*128);
    dd[idx] = W[j] * lng[j];
  } else if (idx < 2054){
    int o = idx - 2048;
    const float* W = (o < 3) ? (Wm + o*128) : (Ws + (o-3)*128);
    float a = 0.f;
    for (int k = 0; k < 128; ++k) a += W[k]*lng[k];
    dd[idx] = a;
  } else if (idx < 2060){
    int o = idx - 2054;
    const float* W = (o < 3) ? (Wm + o*128) : (Ws + (o-3)*128);
    float a = (o < 3) ? bm[o] : bs[o-3];
    for (int k = 0; k < 128; ++k) a += W[k]*lnb[k];
    dd[idx] = a;
  }
}

// ---------------- main fused kernel ----------------
// r18: WAVE-AUTONOMOUS decomposition. Each wave owns 16 batch rows and
// computes ALL 512 gate columns (jt=0..7 sequential, acc=16 AGPR at a time).
// h C/D->A relayout via 4KB wave-PRIVATE LDS scratch (ds ops + lgkmcnt,
// NO __syncthreads). c-states in regs. LN/heads reduced in-wave (shuffles).
// ZERO barriers in main loops -> no lockstep convoy; waves free-run and
// hide each other's latency. Weights re-streamed per wave (L2-hot, ~36GB
// per dispatch; per-XCD L2 floor ~1.0-1.2ms). One barrier total (staging).
__global__ __launch_bounds__(256)
void traj_main(const float* __restrict__ x,
               const unsigned short* __restrict__ pk,
               const float* __restrict__ dd,
               const float* __restrict__ b0g, const float* __restrict__ b1g,
               const float* __restrict__ bdg,
               const float* __restrict__ Wp,
               float* __restrict__ out)
{
  __shared__ __align__(16) unsigned short hs0[4][16*128];   // 16KB wave-private h0
  __shared__ __align__(16) unsigned short hs1[4][16*128];   // 16KB wave-private h1
  __shared__ __align__(16) float cb0[512];                  // bias stages (6KB)
  __shared__ __align__(16) float cb1[512];
  __shared__ __align__(16) float cbd[512];
  __shared__ __align__(16) float hw8[128][8];               // head weights (4KB)
  __shared__ __align__(16) float wp4[128][4];               // Wp[:, :3] (2KB)
  __shared__ __align__(16) float dbl[10][128];              // dbase (5KB)

  const int tid  = threadIdx.x;
  const int w    = tid >> 6;
  const int lane = tid & 63;
  const int lidx = lane & 15;
  const int lgrp = lane >> 4;
  const int rowg = blockIdx.x*64 + w*16;   // this wave's first global row

  // ---- stage constants (cooperative; ONE barrier in whole kernel) ----
  for (int i = tid; i < 512; i += 256){ cb0[i] = b0g[i]; cb1[i] = b1g[i]; cbd[i] = bdg[i]; }
  const float* hwp = dd + 1280;
  for (int i = tid; i < 1024; i += 256){ int c = i >> 3, o = i & 7; hw8[c][o] = (o < 6) ? hwp[o*128 + c] : 0.f; }
  for (int i = tid; i < 512; i += 256){ int c = i >> 2, o = i & 3; wp4[c][o] = (o < 3) ? Wp[c*131 + o] : 0.f; }
  for (int i = tid; i < 1280; i += 256) dbl[i >> 7][i & 127] = dd[i];
  for (int i = lane; i < 16*128; i += 64){ hs0[w][i] = 0; hs1[w][i] = 0; }
  __syncthreads();

  const unsigned short* pw0 = pk + SET0 + lane*8;
  const unsigned short* pw1 = pk + SET1 + lane*8;
  const unsigned short* pw2 = pk + SET2 + lane*8;

  unsigned short* h0s = &hs0[w][0];
  unsigned short* h1s = &hs1[w][0];

  float c0[8][4], c1[8][4];
  #pragma unroll
  for (int jt = 0; jt < 8; ++jt)
    #pragma unroll
    for (int r = 0; r < 4; ++r){ c0[jt][r] = 0.f; c1[jt][r] = 0.f; }

  // ===================== encoder (no barriers) =====================
  #pragma unroll 1
  for (int t = 0; t < NT; ++t){
    // pre-read h0(t-1) A-frags, then overwrite scratch in place
    short8 a0[4];
    #pragma unroll
    for (int kt = 0; kt < 4; ++kt)
      a0[kt] = *(const short8*)&h0s[sidx(lidx, kt*32 + lgrp*8)];
    short8 ax = {0,0,0,0,0,0,0,0};
    if (lgrp == 0){
      const float* xp = &x[(size_t)(rowg + lidx)*90 + t*6];
      #pragma unroll
      for (int j = 0; j < 6; ++j) ax[j] = (short)f2bf(xp[j]);
    }
    // ---- L0: all 8 jt tiles sequentially ----
    #pragma unroll
    for (int jt = 0; jt < 8; ++jt){
      f32x4 acc[4];
      #pragma unroll
      for (int g = 0; g < 4; ++g){
        float b = cb0[g*128 + jt*16 + lidx];
        acc[g] = (f32x4){b, b, b, b};
      }
      #pragma unroll
      for (int kt = 0; kt < 4; ++kt)
        #pragma unroll
        for (int g = 0; g < 4; ++g){
          short8 wv = *(const short8*)&pw0[(size_t)(((jt*4 + g)*5 + kt)*512)];
          acc[g] = __builtin_amdgcn_mfma_f32_16x16x32_bf16(a0[kt], wv, acc[g], 0, 0, 0);
        }
      #pragma unroll
      for (int g = 0; g < 4; ++g){
        short8 wv = *(const short8*)&pw0[(size_t)(((jt*4 + g)*5 + 4)*512)];
        acc[g] = __builtin_amdgcn_mfma_f32_16x16x32_bf16(ax, wv, acc[g], 0, 0, 0);
      }
      #pragma unroll
      for (int r = 0; r < 4; ++r){
        float iv = sigf(acc[0][r]);
        float fv = sigf(acc[1][r]);
        float gv = tanhf_(acc[2][r]);
        float ov = sigf(acc[3][r]);
        float c = fv*c0[jt][r] + iv*gv;
        c0[jt][r] = c;
        h0s[sidx(lgrp*4 + r, jt*16 + lidx)] = f2bf(ov*tanhf_(c));
      }
    }
    // ---- L1: read new h0 + h1(t-1) frags (before h1 overwrite) ----
    short8 an[4], ah[4];
    #pragma unroll
    for (int kt = 0; kt < 4; ++kt){
      an[kt] = *(const short8*)&h0s[sidx(lidx, kt*32 + lgrp*8)];
      ah[kt] = *(const short8*)&h1s[sidx(lidx, kt*32 + lgrp*8)];
    }
    #pragma unroll
    for (int jt = 0; jt < 8; ++jt){
      f32x4 acc[4];
      #pragma unroll
      for (int g = 0; g < 4; ++g){
        float b = cb1[g*128 + jt*16 + lidx];
        acc[g] = (f32x4){b, b, b, b};
      }
      #pragma unroll
      for (int kt = 0; kt < 4; ++kt)
        #pragma unroll
        for (int g = 0; g < 4; ++g){
          short8 wv = *(const short8*)&pw1[(size_t)(((jt*4 + g)*8 + kt)*512)];
          acc[g] = __builtin_amdgcn_mfma_f32_16x16x32_bf16(an[kt], wv, acc[g], 0, 0, 0);
        }
      #pragma unroll
      for (int kt = 4; kt < 8; ++kt)
        #pragma unroll
        for (int g = 0; g < 4; ++g){
          short8 wv = *(const short8*)&pw1[(size_t)(((jt*4 + g)*8 + kt)*512)];
          acc[g] = __builtin_amdgcn_mfma_f32_16x16x32_bf16(ah[kt-4], wv, acc[g], 0, 0, 0);
        }
      #pragma unroll
      for (int r = 0; r < 4; ++r){
        float iv = sigf(acc[0][r]);
        float fv = sigf(acc[1][r]);
        float gv = tanhf_(acc[2][r]);
        float ov = sigf(acc[3][r]);
        float c = fv*c1[jt][r] + iv*gv;
        c1[jt][r] = c;
        h1s[sidx(lgrp*4 + r, jt*16 + lidx)] = f2bf(ov*tanhf_(c));
      }
    }
  }

  // ===================== decoder (no barriers) =====================
  float hb[6], hc[6];
  #pragma unroll
  for (int o = 0; o < 6; ++o){ hb[o] = dd[2048 + o]; hc[o] = dd[2054 + o]; }
  float prev[4][3];
  #pragma unroll
  for (int r = 0; r < 4; ++r)
    #pragma unroll
    for (int o = 0; o < 3; ++o)
      prev[r][o] = x[(size_t)(rowg + lgrp*4 + r)*90 + 84 + o];

  #pragma unroll 1
  for (int s = 0; s < 10; ++s){
    // din = relu(dbase + prev @ Wp3^T) -> wave-private h0 scratch (C/D layout)
    #pragma unroll
    for (int jt = 0; jt < 8; ++jt){
      float dbs = dbl[s][jt*16 + lidx];
      f32x4 wpv = *(const f32x4*)&wp4[jt*16 + lidx][0];
      #pragma unroll
      for (int r = 0; r < 4; ++r){
        float v = dbs + prev[r][0]*wpv[0] + prev[r][1]*wpv[1] + prev[r][2]*wpv[2];
        h0s[sidx(lgrp*4 + r, jt*16 + lidx)] = f2bf(v > 0.f ? v : 0.f);
      }
    }
    // A-frags (din + h1(s-1), pre-read before h1 overwrite)
    short8 ad[4], ah[4];
    #pragma unroll
    for (int kt = 0; kt < 4; ++kt){
      ad[kt] = *(const short8*)&h0s[sidx(lidx, kt*32 + lgrp*8)];
      ah[kt] = *(const short8*)&h1s[sidx(lidx, kt*32 + lgrp*8)];
    }
    float va[4][8];
    #pragma unroll
    for (int r = 0; r < 4; ++r)
      #pragma unroll
      for (int k = 0; k < 8; ++k) va[r][k] = 0.f;

    #pragma unroll
    for (int jt = 0; jt < 8; ++jt){
      f32x4 acc[4];
      #pragma unroll
      for (int g = 0; g < 4; ++g){
        float b = cbd[g*128 + jt*16 + lidx];
        acc[g] = (f32x4){b, b, b, b};
      }
      #pragma unroll
      for (int kt = 0; kt < 4; ++kt)
        #pragma unroll
        for (int g = 0; g < 4; ++g){
          short8 wv = *(const short8*)&pw2[(size_t)(((jt*4 + g)*8 + kt)*512)];
          acc[g] = __builtin_amdgcn_mfma_f32_16x16x32_bf16(ad[kt], wv, acc[g], 0, 0, 0);
        }
      #pragma unroll
      for (int kt = 4; kt < 8; ++kt)
        #pragma unroll
        for (int g = 0; g < 4; ++g){
          short8 wv = *(const short8*)&pw2[(size_t)(((jt*4 + g)*8 + kt)*512)];
          acc[g] = __builtin_amdgcn_mfma_f32_16x16x32_bf16(ah[kt-4], wv, acc[g], 0, 0, 0);
        }
      f32x4 hw0 = *(const f32x4*)&hw8[jt*16 + lidx][0];
      f32x4 hw1 = *(const f32x4*)&hw8[jt*16 + lidx][4];
      #pragma unroll
      for (int r = 0; r < 4; ++r){
        float iv = sigf(acc[0][r]);
        float fv = sigf(acc[1][r]);
        float gv = tanhf_(acc[2][r]);
        float ov = sigf(acc[3][r]);
        float c = fv*c1[jt][r] + iv*gv;
        c1[jt][r] = c;
        float h = ov*tanhf_(c);
        h1s[sidx(lgrp*4 + r, jt*16 + lidx)] = f2bf(h);
        va[r][0] += h;
        va[r][1] += h*h;
        va[r][2] += h*hw0[0]; va[r][3] += h*hw0[1]; va[r][4] += h*hw0[2];
        va[r][5] += h*hw0[3]; va[r][6] += h*hw1[0]; va[r][7] += h*hw1[1];
      }
    }
    // in-wave LN reduce: butterfly over the 16 lanes sharing lgrp
    #pragma unroll
    for (int r = 0; r < 4; ++r)
      #pragma unroll
      for (int d = 1; d < 16; d <<= 1)
        #pragma unroll
        for (int k = 0; k < 8; ++k)
          va[r][k] += __shfl_xor(va[r][k], d);
    // finalize (redundant across the 16 lanes; lidx==0 writes outputs)
    #pragma unroll
    for (int r = 0; r < 4; ++r){
      float mu = va[r][0] * (1.f/128.f);
      float var = va[r][1] * (1.f/128.f) - mu*mu;
      float rs = __builtin_amdgcn_rsqf(var + 1e-5f);
      float p0 = rs*(va[r][2] - mu*hb[0]) + hc[0];
      float p1 = rs*(va[r][3] - mu*hb[1]) + hc[1];
      float p2 = rs*(va[r][4] - mu*hb[2]) + hc[2];
      prev[r][0] = p0; prev[r][1] = p1; prev[r][2] = p2;
      if (lidx == 0){
        size_t ro = (size_t)(rowg + lgrp*4 + r)*30 + (size_t)s*3;
        out[ro + 0] = p0; out[ro + 1] = p1; out[ro + 2] = p2;
        float q0 = rs*(va[r][5] - mu*hb[3]) + hc[3];
        float q1 = rs*(va[r][6] - mu*hb[4]) + hc[4];
        float q2 = rs*(va[r][7] - mu*hb[5]) + hc[5];
        const size_t OFF = (size_t)65536*30;
        out[OFF + ro + 0] = fminf(fmaxf(q0, -6.f), 3.f);
        out[OFF + ro + 1] = fminf(fmaxf(q1, -6.f), 3.f);
        out[OFF + ro + 2] = fminf(fmaxf(q2, -6.f), 3.f);
      }
    }
  }
}

extern "C" void kernel_launch(void* const* d_in, const int* in_sizes, int n_in,
                              void* d_out, int out_size, void* d_ws, size_t ws_size,
                              hipStream_t stream)
{
  const float* x    = (const float*)d_in[0];
  const float* Wih0 = (const float*)d_in[1];
  const float* Whh0 = (const float*)d_in[2];
  const float* b0   = (const float*)d_in[3];
  const float* Wih1 = (const float*)d_in[4];
  const float* Whh1 = (const float*)d_in[5];
  const float* b1   = (const float*)d_in[6];
  const float* Wihd = (const float*)d_in[7];
  const float* Whhd = (const float*)d_in[8];
  const float* bd   = (const float*)d_in[9];
  const float* emb  = (const float*)d_in[10];
  const float* Wp   = (const float*)d_in[11];
  const float* bp   = (const float*)d_in[12];
  const float* Wm   = (const float*)d_in[13];
  const float* bm   = (const float*)d_in[14];
  const float* Ws   = (const float*)d_in[15];
  const float* bs   = (const float*)d_in[16];
  const float* lng  = (const float*)d_in[17];
  const float* lnb  = (const float*)d_in[18];

  unsigned short* pkw = (unsigned short*)d_ws;
  float* dd = (float*)((char*)d_ws + DD_OFF);

  pack_w<<<(PK_TOTAL + 255)/256, 256, 0, stream>>>(Wih0, Whh0, Wih1, Whh1,
                                                   Wihd, Whhd, Wm, Ws, pkw);
  prep_dec<<<17, 128, 0, stream>>>(emb, Wp, bp, Wm, Ws, bm, bs, lng, lnb, dd);
  traj_main<<<1024, 256, 0, stream>>>(x, pkw, dd, b0, b1, bd, Wp, (float*)d_out);
}

// Round 19
// 2019.033 us; speedup vs baseline: 8.0655x; 8.0655x over previous
//
#include <hip/hip_runtime.h>
#include <stdint.h>

typedef __attribute__((ext_vector_type(8))) short short8;
typedef __attribute__((ext_vector_type(4))) float f32x4;

#define NT 15

// packed bf16 weight fragments in d_ws (element offsets, shorts)
#define SET0 0          // L0: 32 (jt,g) pairs x 5 kt x 512
#define SET1 81920      // L1: 32 pairs x 8 kt x 512
#define SET2 212992     // dec: same shape as L1
#define SET3 344064
#define PK_TOTAL 346112
#define DD_OFF (PK_TOTAL*2)   // dbase[1280] | hw[768] | hb[6] | hc[6]  (floats)

__device__ __forceinline__ unsigned short f2bf(float f){
  unsigned int u = __builtin_bit_cast(unsigned int, f);
  u += 0x7fffu + ((u >> 16) & 1u);
  return (unsigned short)(u >> 16);
}
__device__ __forceinline__ float sigf(float x){
  return __builtin_amdgcn_rcpf(1.0f + __expf(-x));
}
__device__ __forceinline__ float tanhf_(float x){
  return 1.0f - 2.0f*__builtin_amdgcn_rcpf(1.0f + __expf(2.0f*x));
}
__device__ __forceinline__ int sidx(int row, int col){
  return row*128 + (col ^ ((row & 7) << 3));
}
__device__ __forceinline__ void BAR(){
  asm volatile("s_waitcnt lgkmcnt(0)" ::: "memory");
  __builtin_amdgcn_s_barrier();
}

// ---------------- prep: pack weights to bf16 MFMA fragments ----------------
__global__ void pack_w(const float* __restrict__ Wih0, const float* __restrict__ Whh0,
                       const float* __restrict__ Wih1, const float* __restrict__ Whh1,
                       const float* __restrict__ Wihd, const float* __restrict__ Whhd,
                       const float* __restrict__ Wm,  const float* __restrict__ Ws,
                       unsigned short* __restrict__ pk)
{
  int idx = blockIdx.x*256 + threadIdx.x;
  if (idx >= PK_TOTAL) return;
  float v = 0.f;
  if (idx >= SET3){
    int e = idx - SET3;
    int j = e & 7, lane = (e >> 3) & 63, kt = e >> 9;
    int n = lane & 15;
    int k = kt*32 + (lane >> 4)*8 + j;
    if (n < 3) v = Wm[n*128 + k];
    else if (n < 6) v = Ws[(n-3)*128 + k];
  } else {
    int set, e;
    if (idx < SET1){ set = 0; e = idx; }
    else if (idx < SET2){ set = 1; e = idx - SET1; }
    else { set = 2; e = idx - SET2; }
    int j = e & 7, lane = (e >> 3) & 63, rest = e >> 9;
    int nf = (set == 0) ? 5 : 8;
    int kt = rest % nf, pair = rest / nf;
    int g = pair & 3, jt = pair >> 2;
    int n = g*128 + jt*16 + (lane & 15);
    int kk = (lane >> 4)*8 + j;
    if (set == 0){
      if (kt < 4) v = Whh0[n*128 + kt*32 + kk];
      else if (kk < 6) v = Wih0[n*6 + kk];
    } else {
      const float* Wi = (set == 1) ? Wih1 : Wihd;
      const float* Wh = (set == 1) ? Whh1 : Whhd;
      v = (kt < 4) ? Wi[n*128 + kt*32 + kk] : Wh[n*128 + (kt-4)*32 + kk];
    }
  }
  pk[idx] = f2bf(v);
}

// decoder constants (see r7)
__global__ void prep_dec(const float* __restrict__ emb, const float* __restrict__ Wp,
                         const float* __restrict__ bp,
                         const float* __restrict__ Wm, const float* __restrict__ Ws,
                         const float* __restrict__ bm, const float* __restrict__ bs,
                         const float* __restrict__ lng, const float* __restrict__ lnb,
                         float* __restrict__ dd)
{
  int idx = blockIdx.x*128 + threadIdx.x;
  if (idx < 1280){
    int s = idx >> 7, j = idx & 127;
    float acc = bp[j];
    for (int k = 0; k < 128; ++k) acc += emb[s*128 + k] * Wp[j*131 + 3 + k];
    dd[idx] = acc;
  } else if (idx < 2048){
    int e = idx - 1280; int o = e >> 7, j = e & 127;
    const float* W = (o < 3) ? (Wm + o*128) : (Ws + (o-3)*128);
    dd[idx] = W[j] * lng[j];
  } else if (idx < 2054){
    int o = idx - 2048;
    const float* W = (o < 3) ? (Wm + o*128) : (Ws + (o-3)*128);
    float a = 0.f;
    for (int k = 0; k < 128; ++k) a += W[k]*lng[k];
    dd[idx] = a;
  } else if (idx < 2060){
    int o = idx - 2054;
    const float* W = (o < 3) ? (Wm + o*128) : (Ws + (o-3)*128);
    float a = (o < 3) ? bm[o] : bs[o-3];
    for (int k = 0; k < 128; ++k) a += W[k]*lnb[k];
    dd[idx] = a;
  }
}

// ---------------- main fused kernel ----------------
// FINAL (= r14, session best 1992us): r11 pipelined encoder (phase k =
// L0(k)+L1(k-1), 16 phases) + one-barrier decoder steps (per-lane redundant
// finalize of s-1 from dbuf'd sred + in-register din + cell MFMA, 11 phases).
// 128V+64A=192 unified -> 2 waves/SIMD, 8 waves/CU, single barrier domain.
// All alternatives measured & rejected: occupancy levers (r12,r13,r16,r17),
// deeper fusion (r15: numerics), wave-autonomous (r18: 8x weight traffic).
__global__ __launch_bounds__(512)
void traj_main(const float* __restrict__ x,
               const unsigned short* __restrict__ pk,
               const float* __restrict__ dd,
               const float* __restrict__ b0g, const float* __restrict__ b1g,
               const float* __restrict__ bdg,
               const float* __restrict__ Wp,
               float* __restrict__ out)
{
  __shared__ __align__(16) union {
    unsigned short h0[2][64*128];                 // encoder h0 ping-pong (32KB)
    struct {
      float sred[2][8][64][8];                    // dbuf'd partials (32KB)
      float wp3[128][4];                          // Wp[:, :3] staged (2KB)
      float dbl[10][128];                         // dbase staged (5KB)
    } d;
  } uA;
  __shared__ __align__(16) unsigned short hB[2][64*128];  // h1 ping-pong (32KB)
  __shared__ __align__(16) union {
    unsigned short xs[NT*64*8];                       // 15360B (encoder)
    struct { float om[64][30]; float os[64][30]; } o; // 15360B (decoder)
  } u2;

  const int tid  = threadIdx.x;
  const int w    = tid >> 6;
  const int lane = tid & 63;
  const int lidx = lane & 15;
  const int lgrp = lane >> 4;
  const int col  = w*16 + lidx;
  const int row0 = blockIdx.x * 64;

  for (int i = tid; i < 64*128; i += 512){ uA.h0[1][i] = 0; hB[1][i] = 0; }
  for (int i = tid; i < NT*64*8; i += 512){
    int k8 = i & 7, rt = i >> 3;
    int r = rt & 63, t = rt >> 6;
    u2.xs[i] = (k8 < 6) ? f2bf(x[(size_t)(row0 + r)*90 + t*6 + k8])
                        : (unsigned short)0;
  }

  float b0v[4], b1v[4];
  #pragma unroll
  for (int g = 0; g < 4; ++g){ b0v[g] = b0g[g*128 + col]; b1v[g] = b1g[g*128 + col]; }

  float c0[4][4], c1[4][4];
  #pragma unroll
  for (int m = 0; m < 4; ++m)
    #pragma unroll
    for (int r = 0; r < 4; ++r){ c0[m][r] = 0.f; c1[m][r] = 0.f; }

  __syncthreads();

  const unsigned short* pw0 = pk + SET0 + (w*4)*(5*512) + lane*8;
  const unsigned short* pw1 = pk + SET1 + (w*4)*(8*512) + lane*8;
  const unsigned short* pw2 = pk + SET2 + (w*4)*(8*512) + lane*8;
  const short8 z8 = {0,0,0,0,0,0,0,0};

  // ======== pipelined encoder: phase k = L0(k) + L1(k-1), 16 phases ========
  #pragma unroll 1
  for (int k = 0; k <= NT; ++k){
    const unsigned short* h0rd = &uA.h0[(k+1)&1][0];
    unsigned short*       h0wr = &uA.h0[k&1][0];
    const unsigned short* h1rd = &hB[k&1][0];
    unsigned short*       h1wr = &hB[(k+1)&1][0];

    if (k < NT){
      f32x4 acc[4][4];
      #pragma unroll
      for (int m = 0; m < 4; ++m)
        #pragma unroll
        for (int g = 0; g < 4; ++g)
          acc[m][g] = (f32x4){b0v[g], b0v[g], b0v[g], b0v[g]};
      #pragma unroll
      for (int kt = 0; kt < 5; ++kt){
        short8 am[4];
        #pragma unroll
        for (int m = 0; m < 4; ++m){
          const int arow = m*16 + lidx;
          if (kt < 4)
            am[m] = *(const short8*)&h0rd[sidx(arow, kt*32 + lgrp*8)];
          else
            am[m] = (lgrp == 0) ? *(const short8*)&u2.xs[(k*64 + arow)*8] : z8;
        }
        #pragma unroll
        for (int g = 0; g < 4; ++g){
          short8 wv = *(const short8*)&pw0[(g*5 + kt)*512];
          #pragma unroll
          for (int m = 0; m < 4; ++m)
            acc[m][g] = __builtin_amdgcn_mfma_f32_16x16x32_bf16(am[m], wv, acc[m][g], 0, 0, 0);
        }
      }
      #pragma unroll
      for (int m = 0; m < 4; ++m)
        #pragma unroll
        for (int r = 0; r < 4; ++r){
          float iv = sigf(acc[m][0][r]);
          float fv = sigf(acc[m][1][r]);
          float gv = tanhf_(acc[m][2][r]);
          float ov = sigf(acc[m][3][r]);
          float c = fv*c0[m][r] + iv*gv;
          c0[m][r] = c;
          h0wr[sidx(m*16 + lgrp*4 + r, col)] = f2bf(ov*tanhf_(c));
        }
    }

    if (k >= 1){
      f32x4 acc[4][4];
      #pragma unroll
      for (int m = 0; m < 4; ++m)
        #pragma unroll
        for (int g = 0; g < 4; ++g)
          acc[m][g] = (f32x4){b1v[g], b1v[g], b1v[g], b1v[g]};
      #pragma unroll
      for (int kt = 0; kt < 8; ++kt){
        short8 am[4];
        #pragma unroll
        for (int m = 0; m < 4; ++m){
          const int arow = m*16 + lidx;
          if (kt < 4)
            am[m] = *(const short8*)&h0rd[sidx(arow, kt*32 + lgrp*8)];
          else
            am[m] = *(const short8*)&h1rd[sidx(arow, (kt-4)*32 + lgrp*8)];
        }
        #pragma unroll
        for (int g = 0; g < 4; ++g){
          short8 wv = *(const short8*)&pw1[(g*8 + kt)*512];
          #pragma unroll
          for (int m = 0; m < 4; ++m)
            acc[m][g] = __builtin_amdgcn_mfma_f32_16x16x32_bf16(am[m], wv, acc[m][g], 0, 0, 0);
        }
      }
      #pragma unroll
      for (int m = 0; m < 4; ++m)
        #pragma unroll
        for (int r = 0; r < 4; ++r){
          float iv = sigf(acc[m][0][r]);
          float fv = sigf(acc[m][1][r]);
          float gv = tanhf_(acc[m][2][r]);
          float ov = sigf(acc[m][3][r]);
          float c = fv*c1[m][r] + iv*gv;
          c1[m][r] = c;
          h1wr[sidx(m*16 + lgrp*4 + r, col)] = f2bf(ov*tanhf_(c));
        }
    }
    BAR();
  }
  // h1[14] lives in hB[0]; uA.h0 dead -> decoder overlay becomes live.

  // ===================== decoder =====================
  const float* dbase = dd;
  const float* hwp   = dd + 1280;
  const float* hbp   = dd + 2048;
  const float* hcp   = dd + 2054;

  float bdv[4];
  #pragma unroll
  for (int g = 0; g < 4; ++g) bdv[g] = bdg[g*128 + col];
  float hwv[6], hbv[6], hcv[6];
  #pragma unroll
  for (int o = 0; o < 6; ++o){
    hwv[o] = hwp[o*128 + col];
    hbv[o] = hbp[o];
    hcv[o] = hcp[o];
  }

  // stage Wp3 + dbase into LDS (uA overlay)
  for (int i = tid; i < 128*4; i += 512){
    int k = i >> 2, o = i & 3;
    uA.d.wp3[k][o] = (o < 3) ? Wp[k*131 + o] : 0.f;
  }
  for (int i = tid; i < 1280; i += 512)
    uA.d.dbl[i >> 7][i & 127] = dbase[i];
  __syncthreads();   // overlay + u2 role switch

  int hcur = 0, hnew = 1;
  #pragma unroll 1
  for (int s = 0; s <= 10; ++s){
    // ---- A: finalize step s-1 (redundant per-lane) / prev0 from x ----
    float prevr[4][3];
    if (s == 0){
      #pragma unroll
      for (int m = 0; m < 4; ++m){
        const int row = m*16 + lidx;
        #pragma unroll
        for (int o = 0; o < 3; ++o)
          prevr[m][o] = x[(size_t)(row0 + row)*90 + 14*6 + o];
      }
    } else {
      const float (*sr)[64][8] = uA.d.sred[(s + 1) & 1];
      #pragma unroll
      for (int m = 0; m < 4; ++m){
        const int row = m*16 + lidx;
        float s1 = 0.f, s2 = 0.f;
        float A0 = 0.f, A1 = 0.f, A2 = 0.f, A3 = 0.f, A4 = 0.f, A5 = 0.f;
        #pragma unroll
        for (int ww = 0; ww < 8; ++ww){
          f32x4 v0 = *(const f32x4*)&sr[ww][row][0];
          f32x4 v1 = *(const f32x4*)&sr[ww][row][4];
          s1 += v0[0]; s2 += v0[1]; A0 += v0[2]; A1 += v0[3];
          A2 += v1[0]; A3 += v1[1]; A4 += v1[2]; A5 += v1[3];
        }
        float mu = s1 * (1.f/128.f);
        float var = s2 * (1.f/128.f) - mu*mu;
        float rs = __builtin_amdgcn_rsqf(var + 1e-5f);
        prevr[m][0] = rs*(A0 - mu*hbv[0]) + hcv[0];
        prevr[m][1] = rs*(A1 - mu*hbv[1]) + hcv[1];
        prevr[m][2] = rs*(A2 - mu*hbv[2]) + hcv[2];
        if (w == 0 && lgrp == 0){
          u2.o.om[row][(s-1)*3 + 0] = prevr[m][0];
          u2.o.om[row][(s-1)*3 + 1] = prevr[m][1];
          u2.o.om[row][(s-1)*3 + 2] = prevr[m][2];
          float q3 = rs*(A3 - mu*hbv[3]) + hcv[3];
          float q4 = rs*(A4 - mu*hbv[4]) + hcv[4];
          float q5 = rs*(A5 - mu*hbv[5]) + hcv[5];
          u2.o.os[row][(s-1)*3 + 0] = fminf(fmaxf(q3, -6.f), 3.f);
          u2.o.os[row][(s-1)*3 + 1] = fminf(fmaxf(q4, -6.f), 3.f);
          u2.o.os[row][(s-1)*3 + 2] = fminf(fmaxf(q5, -6.f), 3.f);
        }
      }
    }

    if (s < 10){
      // ---- B: cell (kt-outer; kt<4 A-frags computed IN-REG from prevr) ----
      const unsigned short* bh = &hB[hcur][0];
      unsigned short* bhn = &hB[hnew][0];
      float (*srw)[64][8] = uA.d.sred[s & 1];

      f32x4 acc[4][4];
      #pragma unroll
      for (int m = 0; m < 4; ++m)
        #pragma unroll
        for (int g = 0; g < 4; ++g)
          acc[m][g] = (f32x4){bdv[g], bdv[g], bdv[g], bdv[g]};
      #pragma unroll
      for (int kt = 0; kt < 8; ++kt){
        short8 am[4];
        if (kt < 4){
          const int k0 = kt*32 + lgrp*8;
          f32x4 db0 = *(const f32x4*)&uA.d.dbl[s][k0];
          f32x4 db1 = *(const f32x4*)&uA.d.dbl[s][k0 + 4];
          f32x4 wpv[8];
          #pragma unroll
          for (int j = 0; j < 8; ++j)
            wpv[j] = *(const f32x4*)&uA.d.wp3[k0 + j][0];
          #pragma unroll
          for (int m = 0; m < 4; ++m){
            short8 a;
            #pragma unroll
            for (int j = 0; j < 8; ++j){
              float db = (j < 4) ? db0[j] : db1[j-4];
              float v = db + prevr[m][0]*wpv[j][0] + prevr[m][1]*wpv[j][1]
                           + prevr[m][2]*wpv[j][2];
              a[j] = (short)f2bf(v > 0.f ? v : 0.f);
            }
            am[m] = a;
          }
        } else {
          #pragma unroll
          for (int m = 0; m < 4; ++m)
            am[m] = *(const short8*)&bh[sidx(m*16 + lidx, (kt-4)*32 + lgrp*8)];
        }
        #pragma unroll
        for (int g = 0; g < 4; ++g){
          short8 wv = *(const short8*)&pw2[(g*8 + kt)*512];
          #pragma unroll
          for (int m = 0; m < 4; ++m)
            acc[m][g] = __builtin_amdgcn_mfma_f32_16x16x32_bf16(am[m], wv, acc[m][g], 0, 0, 0);
        }
      }
      #pragma unroll
      for (int m = 0; m < 4; ++m)
        #pragma unroll
        for (int r = 0; r < 4; ++r){
          float iv = sigf(acc[m][0][r]);
          float fv = sigf(acc[m][1][r]);
          float gv = tanhf_(acc[m][2][r]);
          float ov = sigf(acc[m][3][r]);
          float c = fv*c1[m][r] + iv*gv;
          c1[m][r] = c;
          float h = ov*tanhf_(c);
          const int row = m*16 + lgrp*4 + r;
          bhn[sidx(row, col)] = f2bf(h);
          float vals[8];
          vals[0] = h; vals[1] = h*h;
          #pragma unroll
          for (int o = 0; o < 6; ++o) vals[2+o] = h*hwv[o];
          #pragma unroll
          for (int d = 1; d < 16; d <<= 1)
            #pragma unroll
            for (int kk = 0; kk < 8; ++kk)
              vals[kk] += __shfl_xor(vals[kk], d);
          if (lidx == 0){
            *(f32x4*)&srw[w][row][0] = (f32x4){vals[0], vals[1], vals[2], vals[3]};
            *(f32x4*)&srw[w][row][4] = (f32x4){vals[4], vals[5], vals[6], vals[7]};
          }
        }
      BAR();
      int tswap = hcur; hcur = hnew; hnew = tswap;
    }
  }

  __syncthreads();
  // ---- single coalesced output flush ----
  for (int i = tid; i < 1920; i += 512){
    int r = i / 30, cx = i - r*30;
    out[(size_t)(row0 + r)*30 + cx] = u2.o.om[r][cx];
    out[(size_t)65536*30 + (size_t)(row0 + r)*30 + cx] = u2.o.os[r][cx];
  }
}

extern "C" void kernel_launch(void* const* d_in, const int* in_sizes, int n_in,
                              void* d_out, int out_size, void* d_ws, size_t ws_size,
                              hipStream_t stream)
{
  const float* x    = (const float*)d_in[0];
  const float* Wih0 = (const float*)d_in[1];
  const float* Whh0 = (const float*)d_in[2];
  const float* b0   = (const float*)d_in[3];
  const float* Wih1 = (const float*)d_in[4];
  const float* Whh1 = (const float*)d_in[5];
  const float* b1   = (const float*)d_in[6];
  const float* Wihd = (const float*)d_in[7];
  const float* Whhd = (const float*)d_in[8];
  const float* bd   = (const float*)d_in[9];
  const float* emb  = (const float*)d_in[10];
  const float* Wp   = (const float*)d_in[11];
  const float* bp   = (const float*)d_in[12];
  const float* Wm   = (const float*)d_in[13];
  const float* bm   = (const float*)d_in[14];
  const float* Ws   = (const float*)d_in[15];
  const float* bs   = (const float*)d_in[16];
  const float* lng  = (const float*)d_in[17];
  const float* lnb  = (const float*)d_in[18];

  unsigned short* pkw = (unsigned short*)d_ws;
  float* dd = (float*)((char*)d_ws + DD_OFF);

  pack_w<<<(PK_TOTAL + 255)/256, 256, 0, stream>>>(Wih0, Whh0, Wih1, Whh1,
                                                   Wihd, Whhd, Wm, Ws, pkw);
  prep_dec<<<17, 128, 0, stream>>>(emb, Wp, bp, Wm, Ws, bm, bs, lng, lnb, dd);
  traj_main<<<1024, 512, 0, stream>>>(x, pkw, dd, b0, b1, bd, Wp, (float*)d_out);
}